// Round 13
// baseline (99.267 us; speedup 1.0000x reference)
//
#include <hip/hip_runtime.h>
#include <math.h>

namespace {

constexpr int B = 2048;
constexpr int C = 20000;
constexpr int D = 512;
constexpr int LMAX = 8;

constexpr int BMt = 128;                     // GEMM block rows
constexpr int BNt = 256;                     // GEMM block cols
constexpr int NROWT = B / BMt;               // 16 row tiles
constexpr int NPAN  = (C + BNt - 1) / BNt;   // 79 col panels (last: 32 valid of 256)
constexpr int KST   = D / 64;                // 8 K-steps
constexpr int SLOTS_A = BMt * 4;             // 512  16B-slots per (tile,kstep)
constexpr int SLOTS_B = BNt * 4;             // 1024
constexpr int NWG   = NROWT * NPAN;          // 1264 (divisible by 8 XCDs)

constexpr float S_SCALE = 30.0f;
constexpr float COS_M = 0.87758256189037271f;   // cos(0.5)
constexpr float SIN_M = 0.47942553860420301f;   // sin(0.5)
constexpr float TH    = -0.87758256189037271f;  // cos(pi - 0.5)
constexpr float MM    = 0.23971276930210156f;   // sin(pi - 0.5) * 0.5
constexpr float MFIX  = 30.0f;                  // fixed softmax shift: |logits| <= 30

typedef float f32x16 __attribute__((ext_vector_type(16)));

__device__ __forceinline__ void mfma_fp8_t(f32x16& acc, unsigned long long bfrag,
                                           unsigned long long afrag) {
    // transposed: builtin(A=bfrag, B=afrag) -> D cols (lane&31) = logit ROWS
    acc = __builtin_amdgcn_mfma_f32_32x32x16_fp8_fp8((long)bfrag, (long)afrag, acc, 0, 0, 0);
}

// 8 fp32 -> 8 fp8 e4m3 bytes (hardware RNE pack), element j = byte j
__device__ __forceinline__ unsigned long long pack8_fp8(const float* xs, float sc) {
    int d0 = __builtin_amdgcn_cvt_pk_fp8_f32(xs[0] * sc, xs[1] * sc, 0, false);
    d0 = __builtin_amdgcn_cvt_pk_fp8_f32(xs[2] * sc, xs[3] * sc, d0, true);
    int d1 = __builtin_amdgcn_cvt_pk_fp8_f32(xs[4] * sc, xs[5] * sc, 0, false);
    d1 = __builtin_amdgcn_cvt_pk_fp8_f32(xs[6] * sc, xs[7] * sc, d1, true);
    return (unsigned long long)(unsigned)d0 | ((unsigned long long)(unsigned)d1 << 32);
}

__device__ __forceinline__ float wave_sum(float v) {
    #pragma unroll
    for (int off = 1; off < 64; off <<= 1) v += __shfl_xor(v, off, 64);
    return v;
}

// Single-pass fused norm+pack: block = 32 rows, 8 threads per row, thread owns
// one 64-wide k-step (64 floats live in registers). Norm via 3 shfl_xor within
// the 8-lane group; pack fp8 from registers. Reads source exactly ONCE.
// Panel layout (PR = panel rows): slot u = q2*64 + l, q2 = (lr>>5)*2 + k32;
// lane l = (lr&31) + 32*g holds k = k32*32 + h*16 + g*8 + j (h -> .x/.y).
template<int PR>
__global__ void pack_norm_kernel(const float* __restrict__ x, ulonglong2* __restrict__ P,
                                 float* __restrict__ nrm_out, int nrows) {
    const int t = threadIdx.x;
    const int r = blockIdx.x * 32 + (t >> 3);
    const int s = t & 7;                       // owned k-step
    float xs[64];
    float s2 = 0.0f;
    const float4* p = reinterpret_cast<const float4*>(x + (size_t)r * D + s * 64);
    #pragma unroll
    for (int i = 0; i < 16; ++i) {
        const float4 v = p[i];
        xs[i*4+0] = v.x; xs[i*4+1] = v.y; xs[i*4+2] = v.z; xs[i*4+3] = v.w;
        s2 += v.x*v.x + v.y*v.y + v.z*v.z + v.w*v.w;
    }
    s2 += __shfl_xor(s2, 1, 64);
    s2 += __shfl_xor(s2, 2, 64);
    s2 += __shfl_xor(s2, 4, 64);
    const float nrm = sqrtf(s2);
    const float inv = 1.0f / fmaxf(nrm, 1e-8f);
    if (s == 0) nrm_out[r] = nrm;

    const int pan = r / PR, lr = r % PR;
    const int mfr = lr >> 5, c31 = lr & 31;
    ulonglong2* blk = P + (size_t)(pan * KST + s) * (PR * 4);
    #pragma unroll
    for (int k32 = 0; k32 < 2; ++k32) {
        #pragma unroll
        for (int g = 0; g < 2; ++g) {
            const unsigned long long lo = pack8_fp8(&xs[k32*32 + g*8], inv);        // h=0
            const unsigned long long hi = pack8_fp8(&xs[k32*32 + 16 + g*8], inv);   // h=1
            blk[(mfr*2 + k32)*64 + c31 + 32*g] = make_ulonglong2(lo, hi);
        }
    }
}

// FP8 MFMA GEMM, 128x256 block tile, 4 waves each 64x128 (2 m-frags x 4 n-frags:
// 32 MFMA per 12 fragment loads per k-step -> 33% fewer bytes per MFMA-cycle).
// Fragments global->VGPR, explicit 2-deep pipeline, no LDS staging/barriers.
// Transposed accumulate: lane&31 owns one logit ROW.
// pZ[row][panel] = sum_cols exp(30*cos - 30).
__global__ __launch_bounds__(256, 2) void
gemm_mfma_kernel(const ulonglong2* __restrict__ Ap, const ulonglong2* __restrict__ Bp,
                 float* __restrict__ pZ)
{
    __shared__ float sRed[BMt][2];
    const int wgid = blockIdx.x;
    const int swz = (wgid & 7) * (NWG / 8) + (wgid >> 3);   // bijective (NWG%8==0)
    const int bx = swz & 15;          // row tile (16)
    const int by = swz >> 4;          // panel (0..78)
    const int tid  = threadIdx.x;
    const int lane = tid & 63;
    const int half = lane >> 5, l31 = lane & 31;
    const int w    = tid >> 6;
    const int wm   = w >> 1;          // 0..1: rows wm*64
    const int wnn  = w & 1;           // 0..1: cols wnn*128

    const ulonglong2* Aw = Ap + (size_t)bx * KST * SLOTS_A + (wm * 4) * 64 + lane;
    const ulonglong2* Bw = Bp + (size_t)by * KST * SLOTS_B + (wnn * 8) * 64 + lane;

    f32x16 am0n0, am0n1, am0n2, am0n3, am1n0, am1n1, am1n2, am1n3;
    #pragma unroll
    for (int i = 0; i < 16; ++i) {
        am0n0[i]=0.f; am0n1[i]=0.f; am0n2[i]=0.f; am0n3[i]=0.f;
        am1n0[i]=0.f; am1n1[i]=0.f; am1n2[i]=0.f; am1n3[i]=0.f;
    }

    // cur fragments: a[mi][k32] (4), b[nj][k32] (8)
    ulonglong2 ca00 = Aw[0],   ca01 = Aw[64],   ca10 = Aw[128],  ca11 = Aw[192];
    ulonglong2 cb00 = Bw[0],   cb01 = Bw[64],   cb10 = Bw[128],  cb11 = Bw[192];
    ulonglong2 cb20 = Bw[256], cb21 = Bw[320],  cb30 = Bw[384],  cb31 = Bw[448];

    #pragma unroll
    for (int s = 0; s < KST; ++s) {
        ulonglong2 na00, na01, na10, na11;
        ulonglong2 nb00, nb01, nb10, nb11, nb20, nb21, nb30, nb31;
        if (s + 1 < KST) {                       // issue next-step loads FIRST
            const ulonglong2* As = Aw + (s + 1) * SLOTS_A;
            const ulonglong2* Bs = Bw + (s + 1) * SLOTS_B;
            na00 = As[0];   na01 = As[64];  na10 = As[128]; na11 = As[192];
            nb00 = Bs[0];   nb01 = Bs[64];  nb10 = Bs[128]; nb11 = Bs[192];
            nb20 = Bs[256]; nb21 = Bs[320]; nb30 = Bs[384]; nb31 = Bs[448];
        }
        // 32 MFMAs: (k32,h) x mi(2) x nj(4)
        mfma_fp8_t(am0n0, cb00.x, ca00.x); mfma_fp8_t(am1n0, cb00.x, ca10.x);
        mfma_fp8_t(am0n1, cb10.x, ca00.x); mfma_fp8_t(am1n1, cb10.x, ca10.x);
        mfma_fp8_t(am0n2, cb20.x, ca00.x); mfma_fp8_t(am1n2, cb20.x, ca10.x);
        mfma_fp8_t(am0n3, cb30.x, ca00.x); mfma_fp8_t(am1n3, cb30.x, ca10.x);
        mfma_fp8_t(am0n0, cb00.y, ca00.y); mfma_fp8_t(am1n0, cb00.y, ca10.y);
        mfma_fp8_t(am0n1, cb10.y, ca00.y); mfma_fp8_t(am1n1, cb10.y, ca10.y);
        mfma_fp8_t(am0n2, cb20.y, ca00.y); mfma_fp8_t(am1n2, cb20.y, ca10.y);
        mfma_fp8_t(am0n3, cb30.y, ca00.y); mfma_fp8_t(am1n3, cb30.y, ca10.y);
        mfma_fp8_t(am0n0, cb01.x, ca01.x); mfma_fp8_t(am1n0, cb01.x, ca11.x);
        mfma_fp8_t(am0n1, cb11.x, ca01.x); mfma_fp8_t(am1n1, cb11.x, ca11.x);
        mfma_fp8_t(am0n2, cb21.x, ca01.x); mfma_fp8_t(am1n2, cb21.x, ca11.x);
        mfma_fp8_t(am0n3, cb31.x, ca01.x); mfma_fp8_t(am1n3, cb31.x, ca11.x);
        mfma_fp8_t(am0n0, cb01.y, ca01.y); mfma_fp8_t(am1n0, cb01.y, ca11.y);
        mfma_fp8_t(am0n1, cb11.y, ca01.y); mfma_fp8_t(am1n1, cb11.y, ca11.y);
        mfma_fp8_t(am0n2, cb21.y, ca01.y); mfma_fp8_t(am1n2, cb21.y, ca11.y);
        mfma_fp8_t(am0n3, cb31.y, ca01.y); mfma_fp8_t(am1n3, cb31.y, ca11.y);
        if (s + 1 < KST) {
            ca00 = na00; ca01 = na01; ca10 = na10; ca11 = na11;
            cb00 = nb00; cb01 = nb01; cb10 = nb10; cb11 = nb11;
            cb20 = nb20; cb21 = nb21; cb30 = nb30; cb31 = nb31;
        }
    }

    // ---- epilogue: per-lane row partials, single cross-lane step ----
    float zA = 0.0f;   // row = wm*64 + l31
    float zB = 0.0f;   // row = wm*64 + 32 + l31
    const int cbase = by * BNt + wnn * 128 + 4 * half;
#define EPI_NJ(ACC0, ACC1, NJ)                                                   \
    {                                                                            \
        _Pragma("unroll")                                                        \
        for (int r = 0; r < 16; ++r) {                                           \
            const int cb = cbase + (NJ) * 32 + (r & 3) + 8 * (r >> 2);           \
            zA += (cb < C) ? __expf(fmaf((ACC0)[r], S_SCALE, -MFIX)) : 0.0f;     \
            zB += (cb < C) ? __expf(fmaf((ACC1)[r], S_SCALE, -MFIX)) : 0.0f;     \
        }                                                                        \
    }
    EPI_NJ(am0n0, am1n0, 0)
    EPI_NJ(am0n1, am1n1, 1)
    EPI_NJ(am0n2, am1n2, 2)
    EPI_NJ(am0n3, am1n3, 3)
#undef EPI_NJ
    zA += __shfl_xor(zA, 32, 64);    // combine the two 4-col half-groups
    zB += __shfl_xor(zB, 32, 64);
    if (half == 0) {
        sRed[wm * 64 + l31][wnn]      = zA;
        sRed[wm * 64 + 32 + l31][wnn] = zB;
    }
    __syncthreads();
    if (tid < BMt) {
        pZ[(size_t)(bx * BMt + tid) * NPAN + by] = sRed[tid][0] + sRed[tid][1];
    }
}

// One wave per row: sum NPAN partials (fixed shift M=30), exact fp32 target
// logits + ArcFace margin, correct Z, emit per-row loss.
__global__ void finalize_kernel(const float* __restrict__ f, const float* __restrict__ w,
                                const float* __restrict__ fn, const float* __restrict__ wn,
                                const int* __restrict__ pinds, const int* __restrict__ lengths,
                                const float* __restrict__ pZ, float* __restrict__ loss)
{
    const int b = blockIdx.x;
    const int lane = threadIdx.x;

    float Zp = 0.0f;
    for (int p = lane; p < NPAN; p += 64) Zp += pZ[(size_t)b * NPAN + p];
    Zp = wave_sum(Zp);

    const float4* fp = reinterpret_cast<const float4*>(f + (size_t)b * D);
    const float4 a0 = fp[lane * 2 + 0];
    const float4 a1 = fp[lane * 2 + 1];
    const float fnb = fn[b];
    const int len = lengths[b];

    float opl[LMAX], ops[LMAX];
    int cs[LMAX];
    #pragma unroll
    for (int j = 0; j < LMAX; ++j) {
        const int c = pinds[(size_t)b * LMAX + j];
        cs[j] = c;
        const float4* wp = reinterpret_cast<const float4*>(w + (size_t)c * D);
        const float4 w0 = wp[lane * 2 + 0];
        const float4 w1 = wp[lane * 2 + 1];
        float d = a0.x*w0.x + a0.y*w0.y + a0.z*w0.z + a0.w*w0.w
                + a1.x*w1.x + a1.y*w1.y + a1.z*w1.z + a1.w*w1.w;
        d = wave_sum(d);
        const float cosv = d / fmaxf(fnb * wn[c], 1e-8f);
        const float sine = sqrtf(fminf(fmaxf(1.0f - cosv * cosv, 0.0f), 1.0f));
        float phi = cosv * COS_M - sine * SIN_M;
        phi = (cosv > TH) ? phi : (cosv - MM);
        opl[j] = S_SCALE * cosv;
        ops[j] = S_SCALE * phi;
    }

    // correct Z for unique positive classes (margin applied), then ragged CE
    float Zc = Zp;
    for (int j = 0; j < len; ++j) {
        bool dup = false;
        for (int jj = 0; jj < j; ++jj) dup = dup || (cs[jj] == cs[j]);
        if (!dup) Zc += expf(ops[j] - MFIX) - expf(opl[j] - MFIX);
    }
    const float lZ = logf(Zc);
    float acc = 0.0f;
    for (int j = 0; j < len; ++j) acc += (MFIX + lZ - ops[j]);
    const float Lf = (float)len;
    if (lane == 0) loss[b] = acc / (Lf * Lf);
}

__global__ void reduce_kernel(const float* __restrict__ loss, float* __restrict__ out) {
    __shared__ float sdata[256];
    const int t = threadIdx.x;
    float s = 0.0f;
    for (int i = t; i < B; i += 256) s += loss[i];
    sdata[t] = s;
    __syncthreads();
    for (int off = 128; off > 0; off >>= 1) {
        if (t < off) sdata[t] += sdata[t + off];
        __syncthreads();
    }
    if (t == 0) out[0] = sdata[0] * (1.0f / (float)B);
}

} // anonymous namespace

extern "C" void kernel_launch(void* const* d_in, const int* in_sizes, int n_in,
                              void* d_out, int out_size, void* d_ws, size_t ws_size,
                              hipStream_t stream) {
    const float* f   = (const float*)d_in[0];
    // d_in[1] = labels [B,C] — not needed (reconstructed from pinds/lengths)
    const float* w   = (const float*)d_in[2];
    const int* pinds = (const int*)d_in[3];
    const int* lens  = (const int*)d_in[4];
    float* out = (float*)d_out;

    char* ws = (char*)d_ws;
    size_t off = 0;
    auto alloc = [&](size_t bytes) { void* p = ws + off; off = (off + bytes + 255) & ~(size_t)255; return p; };

    float* wn   = (float*)alloc(C * 4);
    float* fn   = (float*)alloc(B * 4);
    float* pZ   = (float*)alloc((size_t)B * NPAN * 4);
    float* loss = (float*)alloc(B * 4);
    ulonglong2* Ap = (ulonglong2*)alloc((size_t)NROWT * KST * SLOTS_A * 16);
    ulonglong2* Bp = (ulonglong2*)alloc((size_t)NPAN  * KST * SLOTS_B * 16);

    pack_norm_kernel<BMt><<<dim3(B / 32), 256, 0, stream>>>(f, Ap, fn, B);
    pack_norm_kernel<BNt><<<dim3(C / 32), 256, 0, stream>>>(w, Bp, wn, C);
    gemm_mfma_kernel<<<dim3(NWG), 256, 0, stream>>>(Ap, Bp, pZ);
    finalize_kernel<<<dim3(B), 64, 0, stream>>>(f, w, fn, wn, pinds, lens, pZ, loss);
    reduce_kernel<<<dim3(1), 256, 0, stream>>>(loss, out);
}